// Round 7
// baseline (742.942 us; speedup 1.0000x reference)
//
#include <hip/hip_runtime.h>
#include <math.h>

// Problem constants
#define BATCH 128
#define TENC  64
#define NSTEP 63

// Workspace layout (FLOAT offsets)
#define OFF_WA1ET  0         // [256 k][256 j] f32 : W_a1[j][512+k]  (enc part, for enc_proj)
#define OFF_EPT    65536     // [128 b][256 j][64 t] f32
#define OFF_PKH    2162688   // fp16 region (half offsets within):
                             //   PK1: [0,131072)      = [p<4][kk<16][j<256][m<8] = Wa1[j][p*128+kk*8+m]
                             //   PK4: [131072,393216) = [kk<32][q<1024][m<8]     = Whh[q][kk*8+m]
#define OFF_ZX     2359296   // [2 buf][128 b][2 half][256] f32   z-half exchange (dbuf by step parity)
#define OFF_GX     2490368   // [2 buf][128 b][2 half][1024] f32  gate-half exchange
#define OFF_FLAGS  3014656   // [128 b][2 half][2 which] uint  (monotonic step counters; 0=z 1=g)

typedef __attribute__((ext_vector_type(8))) _Float16 h8_t;
typedef __attribute__((ext_vector_type(2))) _Float16 h2_t;

#if defined(__has_builtin)
#if __has_builtin(__builtin_amdgcn_fdot2)
#define FDOT2(a, b, c) __builtin_amdgcn_fdot2((a), (b), (c), false)
#endif
#endif
#ifndef FDOT2
#define FDOT2(a, b, c) ((c) + (float)(a)[0] * (float)(b)[0] + (float)(a)[1] * (float)(b)[1])
#endif

__device__ __forceinline__ h2_t h2of(h8_t v, int i) {   // i must be literal (unrolled)
    h2_t r = {v[2 * i], v[2 * i + 1]};
    return r;
}
__device__ __forceinline__ float ftanh(float x) {
    x = fminf(15.f, fmaxf(-15.f, x));
    float e = __expf(2.f * x);
    return (e - 1.f) * __builtin_amdgcn_rcpf(e + 1.f);
}
__device__ __forceinline__ float fsig(float x) {
    return __builtin_amdgcn_rcpf(1.f + __expf(-x));
}

// ---------------------------------------------------------------------------
// Pre-kernel A: pack weights (fp16 stream-ordered) + WA1ET (f32)
// ---------------------------------------------------------------------------
__global__ void pack_weights(const float* __restrict__ Wa1,
                             const float* __restrict__ Whh,
                             float* __restrict__ ws) {
    int idx = blockIdx.x * blockDim.x + threadIdx.x;
    _Float16* PKH = (_Float16*)(ws + OFF_PKH);
    if (idx < 131072) {
        int m = idx & 7, j = (idx >> 3) & 255, kk = (idx >> 11) & 15, p = idx >> 15;
        int k = p * 128 + kk * 8 + m;
        PKH[idx] = (_Float16)Wa1[j * 768 + k];
    } else if (idx < 393216) {
        int n = idx - 131072;
        int m = n & 7, q = (n >> 3) & 1023, kk = n >> 13;
        PKH[131072 + n] = (_Float16)Whh[q * 256 + kk * 8 + m];
    } else if (idx < 458752) {
        int n = idx - 393216;
        int k = n >> 8, j = n & 255;
        ws[OFF_WA1ET + n] = Wa1[j * 768 + 512 + k];
    }
}

// Pre-kernel A2: zero the exchange flags (every launch, before decoder)
__global__ void zero_flags(float* __restrict__ ws) {
    unsigned* f = (unsigned*)(ws + OFF_FLAGS);
    f[threadIdx.x] = 0u;
}

// ---------------------------------------------------------------------------
// Pre-kernel B: EPT[b][j][t] = b_a1[j] + sum_k enc[b][t][k] * W_a1[j][512+k]
// ---------------------------------------------------------------------------
__global__ void enc_proj_kernel(const float* __restrict__ enc,
                                const float* __restrict__ ba1,
                                float* __restrict__ ws) {
    __shared__ float smem[8448];
    const int b  = blockIdx.x >> 1;
    const int th = blockIdx.x & 1;
    const int t0 = th * 32;
    const int tid = threadIdx.x;

    const float* encb = enc + (b * TENC + t0) * 256;
    for (int c = 0; c < 32; ++c) smem[c * 256 + tid] = encb[c * 256 + tid];
    __syncthreads();

    const int w = tid >> 6, l = tid & 63;
    float acc[8][4];
    #pragma unroll
    for (int a = 0; a < 8; ++a)
        #pragma unroll
        for (int c = 0; c < 4; ++c) acc[a][c] = 0.f;

    const float4* WT = (const float4*)(ws + OFF_WA1ET);
    for (int k = 0; k < 256; ++k) {
        float4 wv = WT[k * 64 + l];
        #pragma unroll
        for (int tt = 0; tt < 8; ++tt) {
            float e = smem[(w * 8 + tt) * 256 + k];
            acc[tt][0] += e * wv.x; acc[tt][1] += e * wv.y;
            acc[tt][2] += e * wv.z; acc[tt][3] += e * wv.w;
        }
    }
    float4 bb = ((const float4*)ba1)[l];
    __syncthreads();
    #pragma unroll
    for (int tt = 0; tt < 8; ++tt) {
        smem[(4 * l + 0) * 33 + w * 8 + tt] = acc[tt][0] + bb.x;
        smem[(4 * l + 1) * 33 + w * 8 + tt] = acc[tt][1] + bb.y;
        smem[(4 * l + 2) * 33 + w * 8 + tt] = acc[tt][2] + bb.z;
        smem[(4 * l + 3) * 33 + w * 8 + tt] = acc[tt][3] + bb.w;
    }
    __syncthreads();
    float* EPT = ws + OFF_EPT + b * 16384;
    for (int c = 0; c < 32; ++c) {
        int i = c * 256 + tid;
        int j = i >> 5, t5 = i & 31;
        EPT[j * 64 + t0 + t5] = smem[j * 33 + t5];
    }
}

// ---------------------------------------------------------------------------
// Main kernel: 256 WGs = 2 per batch (pair (b, b+128)); WG's k-half of the
// z-GEMV is streamed fp16; its W_hh k-half lives in REGISTERS (16 x half8).
// GEMV math uses v_dot2_f32_f16 with h,c mirrored to LDS f16.
// Exchanges (z, g) are double-buffered by step parity; flag ordering audited:
// buffer s&1 is overwritten at step s+2 which transitively requires the
// peer's step-s read via the g-flag chain.
// ---------------------------------------------------------------------------
__global__ __launch_bounds__(1024, 4) void decoder_main(
    const float* __restrict__ enc, const float* __restrict__ yhist,
    const float* __restrict__ Wa2,
    const float* __restrict__ Wfc, const float* __restrict__ bfc,
    const float* __restrict__ wih, const float* __restrict__ bih,
    const float* __restrict__ bhh,
    const float* __restrict__ Wff, const float* __restrict__ bff,
    float* __restrict__ ws, float* __restrict__ out) {

    __shared__ float hc[512];        // f32 state: h = [0,256), c = [256,512)
    __shared__ _Float16 hcf16[512] __attribute__((aligned(16)));  // f16 mirror
    __shared__ float z[256];
    __shared__ float red1[1024];     // P1 partials [4 k-chunks of 64][256 j]
    __shared__ float red2[1024];     // P2 partials [16 j-chunks][64 t]
    __shared__ float red3[1024];     // P3 partials [4 t-chunks][256 e]
    __shared__ float gbuf[1024];
    __shared__ float attnw[64];
    __shared__ float wa2s[256];
    __shared__ float wfcs[257];
    __shared__ float ys[64];
    __shared__ float epl[16384];     // EPT[b] : [256 j][64 t]
    __shared__ float encl[16384];    // enc[b] : [64 t][256 e]

    const int bid  = blockIdx.x;
    const int b    = bid & 127;
    const int h1   = bid >> 7;       // k-half owned by this WG
    const int tid  = threadIdx.x;
    const int lane = tid & 63;
    const int wv   = tid >> 6;

    const _Float16* PKH = (const _Float16*)(ws + OFF_PKH);
    // ---- load own W_hh k-half into registers (persistent, 64 VGPR) ----
    const h8_t* W4 = (const h8_t*)(PKH + 131072) + (16 * h1) * 1024 + tid;
    h8_t w4r[16];
    #pragma unroll
    for (int kk = 0; kk < 16; ++kk) w4r[kk] = W4[kk * 1024];

    // ---- stage per-batch data into LDS once ----
    const float* EPTb = ws + OFF_EPT + b * 16384;
    const float* encb = enc + b * 16384;
    #pragma unroll
    for (int i = 0; i < 16; ++i) {
        epl[i * 1024 + tid]  = EPTb[i * 1024 + tid];
        encl[i * 1024 + tid] = encb[i * 1024 + tid];
    }
    if (tid < 512) { hc[tid] = 0.f; hcf16[tid] = (_Float16)0.f; }
    if (tid < 256) wa2s[tid] = Wa2[tid];
    if (tid < 257) wfcs[tid] = Wfc[tid];
    if (tid < NSTEP) ys[tid] = yhist[b * NSTEP + tid];
    const float bfc0 = bfc[0];
    const float wi   = wih[tid];
    const float bsum = bih[tid] + bhh[tid];
    __syncthreads();

    // P1 (streamed): own 4 chunks of 64 k within half h1
    const int c1 = tid >> 8, j1 = tid & 255;
    const int p1 = 2 * h1 + (c1 >> 1), kk01 = (c1 & 1) * 8;
    const h8_t* W1 = (const h8_t*)PKH + (p1 * 16 + kk01) * 256 + j1;
    const _Float16* hp1 = hcf16 + h1 * 256 + c1 * 64;   // [h;c] k-slice
    const _Float16* hg  = hcf16 + h1 * 128;             // h k-slice for gates

    // exchange buffers / flags (ZX/GX double-buffered by step parity)
    float* ZX = ws + OFF_ZX;
    float* GX = ws + OFF_GX;
    unsigned* FLGown  = (unsigned*)(ws + OFF_FLAGS) + (b * 2 + h1) * 2;
    unsigned* FLGpeer = (unsigned*)(ws + OFF_FLAGS) + (b * 2 + (1 - h1)) * 2;

    for (int step = 0; step < NSTEP; ++step) {
        const unsigned tgt = (unsigned)(step + 1);
        const int buf = step & 1;
        float* ZXown  = ZX + ((buf * 128 + b) * 2 + h1) * 256;
        float* ZXpeer = ZX + ((buf * 128 + b) * 2 + (1 - h1)) * 256;
        float* GXown  = GX + ((buf * 128 + b) * 2 + h1) * 1024;
        float* GXpeer = GX + ((buf * 128 + b) * 2 + (1 - h1)) * 1024;

        // ---- P1 (own k-half, streamed fp16 + dot2): red1[c1][j1] ----
        {
            float a0 = 0.f, a1 = 0.f;
            #pragma unroll 4
            for (int it = 0; it < 8; ++it) {
                h8_t w  = W1[it * 256];
                h8_t hv = *(const h8_t*)(hp1 + it * 8);   // wave-uniform broadcast
                a0 = FDOT2(h2of(w, 0), h2of(hv, 0), a0);
                a1 = FDOT2(h2of(w, 1), h2of(hv, 1), a1);
                a0 = FDOT2(h2of(w, 2), h2of(hv, 2), a0);
                a1 = FDOT2(h2of(w, 3), h2of(hv, 3), a1);
            }
            red1[c1 * 256 + j1] = a0 + a1;
        }
        __syncthreads();                                 // B1: red1 ready
        // ---- combine own z-half, post to peer ----
        if (tid < 256) {
            float zown = red1[tid] + red1[256 + tid] + red1[512 + tid] + red1[768 + tid];
            z[tid] = zown;
            atomicExch(&ZXown[tid], zown);
        }
        __syncthreads();                                 // B2: z atomics drained
        if (tid == 0) atomicExch(&FLGown[0], tgt);

        // ---- P4 from registers: g[q=tid] = h-half @ Whh[q] ----
        float g0 = 0.f, g1 = 0.f;
        #pragma unroll
        for (int kk = 0; kk < 16; ++kk) {
            h8_t hv = *(const h8_t*)(hg + kk * 8);        // broadcast
            h8_t w  = w4r[kk];
            g0 = FDOT2(h2of(w, 0), h2of(hv, 0), g0);
            g1 = FDOT2(h2of(w, 1), h2of(hv, 1), g1);
            g0 = FDOT2(h2of(w, 2), h2of(hv, 2), g0);
            g1 = FDOT2(h2of(w, 3), h2of(hv, 3), g1);
        }
        const float gown = g0 + g1;
        atomicExch(&GXown[tid], gown);                   // post own gate-half
        __syncthreads();                                 // B3: g atomics drained
        if (tid == 0) {
            atomicExch(&FLGown[1], tgt);                 // g-flag
            while (atomicAdd(&FLGpeer[0], 0u) < tgt) { __builtin_amdgcn_s_sleep(1); }
        }
        __syncthreads();                                 // B4: peer z posted
        if (tid < 256) {
            float zp = atomicAdd(&ZXpeer[tid], 0.f);
            z[tid] = z[tid] + zp;                        // commutative -> bit-identical
        }
        __syncthreads();                                 // B5: z full

        // ---- P2: scores partials ----
        {
            float partial = 0.f;
            const int jbase = wv * 16;
            #pragma unroll
            for (int jj = 0; jj < 16; ++jj) {
                const int j = jbase + jj;
                float v = epl[j * 64 + lane] + z[j];
                partial += ftanh(v) * wa2s[j];
            }
            red2[wv * 64 + lane] = partial;
        }
        __syncthreads();                                 // B6: red2 ready
        if (wv == 0) {
            float s = 0.f;
            #pragma unroll
            for (int w2 = 0; w2 < 16; ++w2) s += red2[w2 * 64 + lane];
            float m = s;
            #pragma unroll
            for (int d = 32; d >= 1; d >>= 1) m = fmaxf(m, __shfl_xor(m, d));
            float e = __expf(s - m);
            float su = e;
            #pragma unroll
            for (int d = 32; d >= 1; d >>= 1) su += __shfl_xor(su, d);
            attnw[lane] = e / su;
        }
        __syncthreads();                                 // B7: attnw ready
        // ---- P3: ctx partials ----
        {
            const int e = tid & 255, tc = tid >> 8;
            float partial = 0.f;
            #pragma unroll
            for (int i = 0; i < 16; ++i) {
                const int t = tc * 16 + i;
                partial += attnw[t] * encl[t * 256 + e];
            }
            red3[tc * 256 + e] = partial;
        }
        __syncthreads();                                 // B8: red3 ready

        // ---- ytil: per-wave redundant reduce (all waves, in-register) ----
        float ytil;
        {
            float partial = 0.f;
            #pragma unroll
            for (int q = 0; q < 4; ++q) {
                const int e2 = q * 64 + lane;
                float cv = red3[e2] + red3[256 + e2] + red3[512 + e2] + red3[768 + e2];
                partial += cv * wfcs[e2];
            }
            #pragma unroll
            for (int d = 32; d >= 1; d >>= 1) partial += __shfl_xor(partial, d);
            ytil = partial + wfcs[256] * ys[step] + bfc0;
        }
        if (tid == 0) {
            while (atomicAdd(&FLGpeer[1], 0u) < tgt) { __builtin_amdgcn_s_sleep(1); }
        }
        __syncthreads();                                 // B9: peer g posted
        {
            float gp = atomicAdd(&GXpeer[tid], 0.f);
            gbuf[tid] = gown + gp + ytil * wi + bsum;    // commutative pair sum
        }
        __syncthreads();                                 // B10: gates ready
        // ---- h, c update (redundant in both WGs, bit-identical) ----
        if (tid < 256) {
            float gi = gbuf[tid], gf = gbuf[256 + tid];
            float gg = gbuf[512 + tid], go = gbuf[768 + tid];
            float cn = fsig(gf) * hc[256 + tid] + fsig(gi) * ftanh(gg);
            float hn = fsig(go) * ftanh(cn);
            hc[tid] = hn; hc[256 + tid] = cn;
            hcf16[tid] = (_Float16)hn; hcf16[256 + tid] = (_Float16)cn;
        }
        __syncthreads();                                 // B11: hc ready
    }

    // ---- epilogue: only half 0 writes out ----
    if (h1 == 0 && wv < 2) {
        float partial = 0.f;
        #pragma unroll
        for (int qq = 0; qq < 8; ++qq) {
            const int e2 = qq * 64 + lane;
            float v;
            if (e2 < 256) {
                v = hc[e2];
            } else {
                const int e = e2 - 256;
                v = red3[e] + red3[256 + e] + red3[512 + e] + red3[768 + e];
            }
            partial += v * Wff[wv * 512 + e2];
        }
        #pragma unroll
        for (int d = 32; d >= 1; d >>= 1) partial += __shfl_xor(partial, d);
        if (lane == 0) out[b * 2 + wv] = partial + bff[wv];
    }
}

// ---------------------------------------------------------------------------
extern "C" void kernel_launch(void* const* d_in, const int* in_sizes, int n_in,
                              void* d_out, int out_size, void* d_ws, size_t ws_size,
                              hipStream_t stream) {
    const float* enc = (const float*)d_in[0];
    const float* yh  = (const float*)d_in[1];
    const float* Wa1 = (const float*)d_in[2];
    const float* ba1 = (const float*)d_in[3];
    const float* Wa2 = (const float*)d_in[4];
    // d_in[5] = b_a2 : softmax shift-invariant, unused
    const float* Wfc = (const float*)d_in[6];
    const float* bfc = (const float*)d_in[7];
    const float* Wih = (const float*)d_in[8];
    const float* Whh = (const float*)d_in[9];
    const float* bih = (const float*)d_in[10];
    const float* bhh = (const float*)d_in[11];
    const float* Wff = (const float*)d_in[12];
    const float* bff = (const float*)d_in[13];
    float* ws  = (float*)d_ws;
    float* out = (float*)d_out;

    hipLaunchKernelGGL(pack_weights, dim3(1792), dim3(256), 0, stream, Wa1, Whh, ws);
    hipLaunchKernelGGL(zero_flags, dim3(1), dim3(512), 0, stream, ws);
    hipLaunchKernelGGL(enc_proj_kernel, dim3(256), dim3(256), 0, stream, enc, ba1, ws);
    hipLaunchKernelGGL(decoder_main, dim3(256), dim3(1024), 0, stream,
                       enc, yh, Wa2, Wfc, bfc, Wih, bih, bhh, Wff, bff, ws, out);
}

// Round 8
// 561.110 us; speedup vs baseline: 1.3241x; 1.3241x over previous
//
#include <hip/hip_runtime.h>
#include <math.h>

// Problem constants
#define BATCH 128
#define TENC  64
#define NSTEP 63

// Workspace layout (FLOAT offsets)
#define OFF_WA1ET  0         // [256 k][256 j] f32 : W_a1[j][512+k]  (enc part, for enc_proj)
#define OFF_EPT    65536     // [128 b][256 j][64 t] f32
#define OFF_PKH    2162688   // fp16 region (half offsets within):
                             //   PK1: [0,131072)      = [p<4][kk<16][j<256][m<8] = Wa1[j][p*128+kk*8+m]
                             //   PK4: [131072,393216) = [kk<32][q<1024][m<8]     = Whh[q][kk*8+m]
#define OFF_ZX     2359296   // [2 buf][128 b][2 half][256] f32   z-half exchange (dbuf by step parity)
#define OFF_GX     2490368   // [2 buf][128 b][2 half][1024] f32  gate-half exchange
#define OFF_FLAGS  3014656   // [128 b][2 half][2 which] uint  (monotonic step counters; 0=z 1=g)

typedef __attribute__((ext_vector_type(8))) _Float16 h8_t;
typedef __attribute__((ext_vector_type(2))) _Float16 h2_t;

#if defined(__has_builtin)
#if __has_builtin(__builtin_amdgcn_fdot2)
#define FDOT2(a, b, c) __builtin_amdgcn_fdot2((a), (b), (c), false)
#endif
#endif
#ifndef FDOT2
#define FDOT2(a, b, c) ((c) + (float)(a)[0] * (float)(b)[0] + (float)(a)[1] * (float)(b)[1])
#endif

__device__ __forceinline__ h2_t h2of(h8_t v, int i) {   // i must be literal (unrolled)
    h2_t r = {v[2 * i], v[2 * i + 1]};
    return r;
}
__device__ __forceinline__ float ftanh(float x) {
    x = fminf(15.f, fmaxf(-15.f, x));
    float e = __expf(2.f * x);
    return (e - 1.f) * __builtin_amdgcn_rcpf(e + 1.f);
}
__device__ __forceinline__ float fsig(float x) {
    return __builtin_amdgcn_rcpf(1.f + __expf(-x));
}

// ---------------------------------------------------------------------------
// Pre-kernel A: pack weights (fp16 stream-ordered) + WA1ET (f32)
// ---------------------------------------------------------------------------
__global__ void pack_weights(const float* __restrict__ Wa1,
                             const float* __restrict__ Whh,
                             float* __restrict__ ws) {
    int idx = blockIdx.x * blockDim.x + threadIdx.x;
    _Float16* PKH = (_Float16*)(ws + OFF_PKH);
    if (idx < 131072) {
        int m = idx & 7, j = (idx >> 3) & 255, kk = (idx >> 11) & 15, p = idx >> 15;
        int k = p * 128 + kk * 8 + m;
        PKH[idx] = (_Float16)Wa1[j * 768 + k];
    } else if (idx < 393216) {
        int n = idx - 131072;
        int m = n & 7, q = (n >> 3) & 1023, kk = n >> 13;
        PKH[131072 + n] = (_Float16)Whh[q * 256 + kk * 8 + m];
    } else if (idx < 458752) {
        int n = idx - 393216;
        int k = n >> 8, j = n & 255;
        ws[OFF_WA1ET + n] = Wa1[j * 768 + 512 + k];
    }
}

// Pre-kernel A2: zero the exchange flags (every launch, before decoder)
__global__ void zero_flags(float* __restrict__ ws) {
    unsigned* f = (unsigned*)(ws + OFF_FLAGS);
    f[threadIdx.x] = 0u;
}

// ---------------------------------------------------------------------------
// Pre-kernel B: EPT[b][j][t] = b_a1[j] + sum_k enc[b][t][k] * W_a1[j][512+k]
// ---------------------------------------------------------------------------
__global__ void enc_proj_kernel(const float* __restrict__ enc,
                                const float* __restrict__ ba1,
                                float* __restrict__ ws) {
    __shared__ float smem[8448];
    const int b  = blockIdx.x >> 1;
    const int th = blockIdx.x & 1;
    const int t0 = th * 32;
    const int tid = threadIdx.x;

    const float* encb = enc + (b * TENC + t0) * 256;
    for (int c = 0; c < 32; ++c) smem[c * 256 + tid] = encb[c * 256 + tid];
    __syncthreads();

    const int w = tid >> 6, l = tid & 63;
    float acc[8][4];
    #pragma unroll
    for (int a = 0; a < 8; ++a)
        #pragma unroll
        for (int c = 0; c < 4; ++c) acc[a][c] = 0.f;

    const float4* WT = (const float4*)(ws + OFF_WA1ET);
    for (int k = 0; k < 256; ++k) {
        float4 wv = WT[k * 64 + l];
        #pragma unroll
        for (int tt = 0; tt < 8; ++tt) {
            float e = smem[(w * 8 + tt) * 256 + k];
            acc[tt][0] += e * wv.x; acc[tt][1] += e * wv.y;
            acc[tt][2] += e * wv.z; acc[tt][3] += e * wv.w;
        }
    }
    float4 bb = ((const float4*)ba1)[l];
    __syncthreads();
    #pragma unroll
    for (int tt = 0; tt < 8; ++tt) {
        smem[(4 * l + 0) * 33 + w * 8 + tt] = acc[tt][0] + bb.x;
        smem[(4 * l + 1) * 33 + w * 8 + tt] = acc[tt][1] + bb.y;
        smem[(4 * l + 2) * 33 + w * 8 + tt] = acc[tt][2] + bb.z;
        smem[(4 * l + 3) * 33 + w * 8 + tt] = acc[tt][3] + bb.w;
    }
    __syncthreads();
    float* EPT = ws + OFF_EPT + b * 16384;
    for (int c = 0; c < 32; ++c) {
        int i = c * 256 + tid;
        int j = i >> 5, t5 = i & 31;
        EPT[j * 64 + t0 + t5] = smem[j * 33 + t5];
    }
}

// ---------------------------------------------------------------------------
// Main kernel: 256 WGs = 2 per batch (pair (b, b+128)); WG streams its k-half
// of BOTH GEMVs from L2 (384 KB/step fp16), math via v_dot2_f32_f16 with h,c
// mirrored to LDS f16 (wide broadcast ds_read_b128 instead of scalar reads).
// NO register residency of weights (round 7 lesson: it spills at 1024 thr).
// Exchanges (z, g) double-buffered by step parity; flag ordering audited.
// ---------------------------------------------------------------------------
__global__ __launch_bounds__(1024, 4) void decoder_main(
    const float* __restrict__ enc, const float* __restrict__ yhist,
    const float* __restrict__ Wa2,
    const float* __restrict__ Wfc, const float* __restrict__ bfc,
    const float* __restrict__ wih, const float* __restrict__ bih,
    const float* __restrict__ bhh,
    const float* __restrict__ Wff, const float* __restrict__ bff,
    float* __restrict__ ws, float* __restrict__ out) {

    __shared__ float hc[512];        // f32 state: h = [0,256), c = [256,512)
    __shared__ _Float16 hcf16[512] __attribute__((aligned(16)));  // f16 mirror
    __shared__ float z[256];
    __shared__ float red1[1024];     // P1 partials [4 k-chunks of 64][256 j]
    __shared__ float red2[1024];     // P2 partials [16 j-chunks][64 t]
    __shared__ float red3[1024];     // P3 partials [4 t-chunks][256 e]
    __shared__ float gbuf[1024];
    __shared__ float attnw[64];
    __shared__ float wa2s[256];
    __shared__ float wfcs[257];
    __shared__ float ys[64];
    __shared__ float epl[16384];     // EPT[b] : [256 j][64 t]
    __shared__ float encl[16384];    // enc[b] : [64 t][256 e]

    const int bid  = blockIdx.x;
    const int b    = bid & 127;
    const int h1   = bid >> 7;       // k-half owned by this WG
    const int tid  = threadIdx.x;
    const int lane = tid & 63;
    const int wv   = tid >> 6;

    const _Float16* PKH = (const _Float16*)(ws + OFF_PKH);

    // ---- stage per-batch data into LDS once ----
    const float* EPTb = ws + OFF_EPT + b * 16384;
    const float* encb = enc + b * 16384;
    #pragma unroll
    for (int i = 0; i < 16; ++i) {
        epl[i * 1024 + tid]  = EPTb[i * 1024 + tid];
        encl[i * 1024 + tid] = encb[i * 1024 + tid];
    }
    if (tid < 512) { hc[tid] = 0.f; hcf16[tid] = (_Float16)0.f; }
    if (tid < 256) wa2s[tid] = Wa2[tid];
    if (tid < 257) wfcs[tid] = Wfc[tid];
    if (tid < NSTEP) ys[tid] = yhist[b * NSTEP + tid];
    const float bfc0 = bfc[0];
    const float wi   = wih[tid];
    const float bsum = bih[tid] + bhh[tid];
    __syncthreads();

    // P1 (streamed): own 4 chunks of 64 k within half h1
    const int c1 = tid >> 8, j1 = tid & 255;
    const int p1 = 2 * h1 + (c1 >> 1), kk01 = (c1 & 1) * 8;
    const h8_t* W1 = (const h8_t*)PKH + (p1 * 16 + kk01) * 256 + j1;
    const _Float16* hp1 = hcf16 + h1 * 256 + c1 * 64;   // [h;c] k-slice
    // P4 (streamed): own k-half of W_hh, gate q = tid
    const h8_t* W4 = (const h8_t*)(PKH + 131072) + (16 * h1) * 1024 + tid;
    const _Float16* hg  = hcf16 + h1 * 128;             // h k-slice for gates

    // exchange buffers / flags (ZX/GX double-buffered by step parity)
    float* ZX = ws + OFF_ZX;
    float* GX = ws + OFF_GX;
    unsigned* FLGown  = (unsigned*)(ws + OFF_FLAGS) + (b * 2 + h1) * 2;
    unsigned* FLGpeer = (unsigned*)(ws + OFF_FLAGS) + (b * 2 + (1 - h1)) * 2;

    for (int step = 0; step < NSTEP; ++step) {
        const unsigned tgt = (unsigned)(step + 1);
        const int buf = step & 1;
        float* ZXown  = ZX + ((buf * 128 + b) * 2 + h1) * 256;
        float* ZXpeer = ZX + ((buf * 128 + b) * 2 + (1 - h1)) * 256;
        float* GXown  = GX + ((buf * 128 + b) * 2 + h1) * 1024;
        float* GXpeer = GX + ((buf * 128 + b) * 2 + (1 - h1)) * 1024;

        // ---- P1 (own k-half, streamed fp16 + dot2): red1[c1][j1] ----
        {
            float a0 = 0.f, a1 = 0.f;
            #pragma unroll 4
            for (int it = 0; it < 8; ++it) {
                h8_t w  = W1[it * 256];
                h8_t hv = *(const h8_t*)(hp1 + it * 8);   // wave-uniform broadcast
                a0 = FDOT2(h2of(w, 0), h2of(hv, 0), a0);
                a1 = FDOT2(h2of(w, 1), h2of(hv, 1), a1);
                a0 = FDOT2(h2of(w, 2), h2of(hv, 2), a0);
                a1 = FDOT2(h2of(w, 3), h2of(hv, 3), a1);
            }
            red1[c1 * 256 + j1] = a0 + a1;
        }
        __syncthreads();                                 // B1: red1 ready
        // ---- combine own z-half, post to peer ----
        if (tid < 256) {
            float zown = red1[tid] + red1[256 + tid] + red1[512 + tid] + red1[768 + tid];
            z[tid] = zown;
            atomicExch(&ZXown[tid], zown);
        }
        __syncthreads();                                 // B2: z atomics drained
        if (tid == 0) atomicExch(&FLGown[0], tgt);

        // ---- P4 (own k-half, streamed fp16 + dot2): g[q=tid] ----
        float g0 = 0.f, g1 = 0.f;
        #pragma unroll 4
        for (int kk = 0; kk < 16; ++kk) {
            h8_t w  = W4[kk * 1024];
            h8_t hv = *(const h8_t*)(hg + kk * 8);        // broadcast
            g0 = FDOT2(h2of(w, 0), h2of(hv, 0), g0);
            g1 = FDOT2(h2of(w, 1), h2of(hv, 1), g1);
            g0 = FDOT2(h2of(w, 2), h2of(hv, 2), g0);
            g1 = FDOT2(h2of(w, 3), h2of(hv, 3), g1);
        }
        const float gown = g0 + g1;
        atomicExch(&GXown[tid], gown);                   // post own gate-half
        __syncthreads();                                 // B3: g atomics drained
        if (tid == 0) {
            atomicExch(&FLGown[1], tgt);                 // g-flag
            while (atomicAdd(&FLGpeer[0], 0u) < tgt) { __builtin_amdgcn_s_sleep(1); }
        }
        __syncthreads();                                 // B4: peer z posted
        if (tid < 256) {
            float zp = atomicAdd(&ZXpeer[tid], 0.f);
            z[tid] = z[tid] + zp;                        // commutative -> bit-identical
        }
        __syncthreads();                                 // B5: z full

        // ---- P2: scores partials ----
        {
            float partial = 0.f;
            const int jbase = wv * 16;
            #pragma unroll
            for (int jj = 0; jj < 16; ++jj) {
                const int j = jbase + jj;
                float v = epl[j * 64 + lane] + z[j];
                partial += ftanh(v) * wa2s[j];
            }
            red2[wv * 64 + lane] = partial;
        }
        __syncthreads();                                 // B6: red2 ready
        if (wv == 0) {
            float s = 0.f;
            #pragma unroll
            for (int w2 = 0; w2 < 16; ++w2) s += red2[w2 * 64 + lane];
            float m = s;
            #pragma unroll
            for (int d = 32; d >= 1; d >>= 1) m = fmaxf(m, __shfl_xor(m, d));
            float e = __expf(s - m);
            float su = e;
            #pragma unroll
            for (int d = 32; d >= 1; d >>= 1) su += __shfl_xor(su, d);
            attnw[lane] = e / su;
        }
        __syncthreads();                                 // B7: attnw ready
        // ---- P3: ctx partials ----
        {
            const int e = tid & 255, tc = tid >> 8;
            float partial = 0.f;
            #pragma unroll
            for (int i = 0; i < 16; ++i) {
                const int t = tc * 16 + i;
                partial += attnw[t] * encl[t * 256 + e];
            }
            red3[tc * 256 + e] = partial;
        }
        __syncthreads();                                 // B8: red3 ready

        // ---- ytil: per-wave redundant reduce (all waves, in-register) ----
        float ytil;
        {
            float partial = 0.f;
            #pragma unroll
            for (int q = 0; q < 4; ++q) {
                const int e2 = q * 64 + lane;
                float cv = red3[e2] + red3[256 + e2] + red3[512 + e2] + red3[768 + e2];
                partial += cv * wfcs[e2];
            }
            #pragma unroll
            for (int d = 32; d >= 1; d >>= 1) partial += __shfl_xor(partial, d);
            ytil = partial + wfcs[256] * ys[step] + bfc0;
        }
        if (tid == 0) {
            while (atomicAdd(&FLGpeer[1], 0u) < tgt) { __builtin_amdgcn_s_sleep(1); }
        }
        __syncthreads();                                 // B9: peer g posted
        {
            float gp = atomicAdd(&GXpeer[tid], 0.f);
            gbuf[tid] = gown + gp + ytil * wi + bsum;    // commutative pair sum
        }
        __syncthreads();                                 // B10: gates ready
        // ---- h, c update (redundant in both WGs, bit-identical) ----
        if (tid < 256) {
            float gi = gbuf[tid], gf = gbuf[256 + tid];
            float gg = gbuf[512 + tid], go = gbuf[768 + tid];
            float cn = fsig(gf) * hc[256 + tid] + fsig(gi) * ftanh(gg);
            float hn = fsig(go) * ftanh(cn);
            hc[tid] = hn; hc[256 + tid] = cn;
            hcf16[tid] = (_Float16)hn; hcf16[256 + tid] = (_Float16)cn;
        }
        __syncthreads();                                 // B11: hc ready
    }

    // ---- epilogue: only half 0 writes out ----
    if (h1 == 0 && wv < 2) {
        float partial = 0.f;
        #pragma unroll
        for (int qq = 0; qq < 8; ++qq) {
            const int e2 = qq * 64 + lane;
            float v;
            if (e2 < 256) {
                v = hc[e2];
            } else {
                const int e = e2 - 256;
                v = red3[e] + red3[256 + e] + red3[512 + e] + red3[768 + e];
            }
            partial += v * Wff[wv * 512 + e2];
        }
        #pragma unroll
        for (int d = 32; d >= 1; d >>= 1) partial += __shfl_xor(partial, d);
        if (lane == 0) out[b * 2 + wv] = partial + bff[wv];
    }
}

// ---------------------------------------------------------------------------
extern "C" void kernel_launch(void* const* d_in, const int* in_sizes, int n_in,
                              void* d_out, int out_size, void* d_ws, size_t ws_size,
                              hipStream_t stream) {
    const float* enc = (const float*)d_in[0];
    const float* yh  = (const float*)d_in[1];
    const float* Wa1 = (const float*)d_in[2];
    const float* ba1 = (const float*)d_in[3];
    const float* Wa2 = (const float*)d_in[4];
    // d_in[5] = b_a2 : softmax shift-invariant, unused
    const float* Wfc = (const float*)d_in[6];
    const float* bfc = (const float*)d_in[7];
    const float* Wih = (const float*)d_in[8];
    const float* Whh = (const float*)d_in[9];
    const float* bih = (const float*)d_in[10];
    const float* bhh = (const float*)d_in[11];
    const float* Wff = (const float*)d_in[12];
    const float* bff = (const float*)d_in[13];
    float* ws  = (float*)d_ws;
    float* out = (float*)d_out;

    hipLaunchKernelGGL(pack_weights, dim3(1792), dim3(256), 0, stream, Wa1, Whh, ws);
    hipLaunchKernelGGL(zero_flags, dim3(1), dim3(512), 0, stream, ws);
    hipLaunchKernelGGL(enc_proj_kernel, dim3(256), dim3(256), 0, stream, enc, ba1, ws);
    hipLaunchKernelGGL(decoder_main, dim3(256), dim3(1024), 0, stream,
                       enc, yh, Wa2, Wfc, bfc, Wih, bih, bhh, Wff, bff, ws, out);
}

// Round 9
// 506.118 us; speedup vs baseline: 1.4679x; 1.1087x over previous
//
#include <hip/hip_runtime.h>
#include <math.h>

// Problem constants
#define BATCH 128
#define TENC  64
#define NSTEP 63

// Workspace layout (FLOAT offsets)
#define OFF_WA1ET  0         // [256 k][256 j] f32 : W_a1[j][512+k]  (enc part, for enc_proj)
#define OFF_EPT    65536     // [128 b][256 j][64 t] f32
#define OFF_PKH    2162688   // fp16 region (half offsets within):
                             //   PK1: [0,131072)      = [p<4][kk<16][j<256][m<8] = Wa1[j][p*128+kk*8+m]
                             //   PKG: [131072,393216) = [h1<2][kk<16][kh<2][q'<512][m<8]
                             //        = Whh[q][k], q = (q'>>7)*256 + h1*128 + (q'&127), k = kh*128+kk*8+m
#define OFF_ZX     2359296   // [128 b][2 half][256] f32   z-half exchange (single-buffered, chain-safe)
#define OFF_HP     2424832   // [128 b][2 half][128] f32   h-slice exchange
#define OFF_FLAGS  2457600   // [128 b][2 half][2] uint    (monotonic; 0=z-flag, 1=h-flag)

typedef __attribute__((ext_vector_type(8))) _Float16 h8_t;
typedef __attribute__((ext_vector_type(2))) _Float16 h2_t;

#if defined(__has_builtin)
#if __has_builtin(__builtin_amdgcn_fdot2)
#define FDOT2(a, b, c) __builtin_amdgcn_fdot2((a), (b), (c), false)
#endif
#endif
#ifndef FDOT2
#define FDOT2(a, b, c) ((c) + (float)(a)[0] * (float)(b)[0] + (float)(a)[1] * (float)(b)[1])
#endif

__device__ __forceinline__ h2_t h2of(h8_t v, int i) {   // i must be literal (unrolled)
    h2_t r = {v[2 * i], v[2 * i + 1]};
    return r;
}
__device__ __forceinline__ float ftanh(float x) {
    x = fminf(15.f, fmaxf(-15.f, x));
    float e = __expf(2.f * x);
    return (e - 1.f) * __builtin_amdgcn_rcpf(e + 1.f);
}
__device__ __forceinline__ float fsig(float x) {
    return __builtin_amdgcn_rcpf(1.f + __expf(-x));
}

// ---------------------------------------------------------------------------
// Pre-kernel A: pack weights (fp16 stream-ordered) + WA1ET (f32)
// ---------------------------------------------------------------------------
__global__ void pack_weights(const float* __restrict__ Wa1,
                             const float* __restrict__ Whh,
                             float* __restrict__ ws) {
    int idx = blockIdx.x * blockDim.x + threadIdx.x;
    _Float16* PKH = (_Float16*)(ws + OFF_PKH);
    if (idx < 131072) {
        // PK1 flat = (p*16+kk)*2048 + j*8 + m -> Wa1[j][p*128+kk*8+m]
        int m = idx & 7, j = (idx >> 3) & 255, kk = (idx >> 11) & 15, p = idx >> 15;
        int k = p * 128 + kk * 8 + m;
        PKH[idx] = (_Float16)Wa1[j * 768 + k];
    } else if (idx < 393216) {
        // PKG flat n = h1*131072 + kk*8192 + kh*4096 + q'*8 + m
        int n = idx - 131072;
        int m = n & 7, qp = (n >> 3) & 511, kh = (n >> 12) & 1, kk = (n >> 13) & 15, h1 = n >> 17;
        int q = ((qp >> 7) << 8) + h1 * 128 + (qp & 127);
        int k = kh * 128 + kk * 8 + m;
        PKH[131072 + n] = (_Float16)Whh[q * 256 + k];
    } else if (idx < 458752) {
        // WA1ET[k][j] = Wa1[j][512+k]  (f32)
        int n = idx - 393216;
        int k = n >> 8, j = n & 255;
        ws[OFF_WA1ET + n] = Wa1[j * 768 + 512 + k];
    }
}

// Pre-kernel A2: zero the exchange flags (every launch, before decoder)
__global__ void zero_flags(float* __restrict__ ws) {
    unsigned* f = (unsigned*)(ws + OFF_FLAGS);
    f[threadIdx.x] = 0u;   // 512 = [128][2][2]
}

// ---------------------------------------------------------------------------
// Pre-kernel B: EPT[b][j][t] = b_a1[j] + sum_k enc[b][t][k] * W_a1[j][512+k]
// ---------------------------------------------------------------------------
__global__ void enc_proj_kernel(const float* __restrict__ enc,
                                const float* __restrict__ ba1,
                                float* __restrict__ ws) {
    __shared__ float smem[8448];
    const int b  = blockIdx.x >> 1;
    const int th = blockIdx.x & 1;
    const int t0 = th * 32;
    const int tid = threadIdx.x;

    const float* encb = enc + (b * TENC + t0) * 256;
    for (int c = 0; c < 32; ++c) smem[c * 256 + tid] = encb[c * 256 + tid];
    __syncthreads();

    const int w = tid >> 6, l = tid & 63;
    float acc[8][4];
    #pragma unroll
    for (int a = 0; a < 8; ++a)
        #pragma unroll
        for (int c = 0; c < 4; ++c) acc[a][c] = 0.f;

    const float4* WT = (const float4*)(ws + OFF_WA1ET);
    for (int k = 0; k < 256; ++k) {
        float4 wv = WT[k * 64 + l];
        #pragma unroll
        for (int tt = 0; tt < 8; ++tt) {
            float e = smem[(w * 8 + tt) * 256 + k];
            acc[tt][0] += e * wv.x; acc[tt][1] += e * wv.y;
            acc[tt][2] += e * wv.z; acc[tt][3] += e * wv.w;
        }
    }
    float4 bb = ((const float4*)ba1)[l];
    __syncthreads();
    #pragma unroll
    for (int tt = 0; tt < 8; ++tt) {
        smem[(4 * l + 0) * 33 + w * 8 + tt] = acc[tt][0] + bb.x;
        smem[(4 * l + 1) * 33 + w * 8 + tt] = acc[tt][1] + bb.y;
        smem[(4 * l + 2) * 33 + w * 8 + tt] = acc[tt][2] + bb.z;
        smem[(4 * l + 3) * 33 + w * 8 + tt] = acc[tt][3] + bb.w;
    }
    __syncthreads();
    float* EPT = ws + OFF_EPT + b * 16384;
    for (int c = 0; c < 32; ++c) {
        int i = c * 256 + tid;
        int j = i >> 5, t5 = i & 31;
        EPT[j * 64 + t0 + t5] = smem[j * 33 + t5];
    }
}

// ---------------------------------------------------------------------------
// Main kernel: 256 WGs = 2 per batch. WG h1 OWNS state slice i in
// [h1*128, h1*128+128) of both h and c, and computes COMPLETE gates for that
// slice (full-k dots, 2 threads/gate) -> no gate exchange. P1's k-slice is
// exactly the owned state -> no peer state needed. Only exchanges: z-partials
// (hidden under P4's stream) and the 128-f32 h-slice (hidden under step turn).
// ---------------------------------------------------------------------------
__global__ __launch_bounds__(1024, 4) void decoder_main(
    const float* __restrict__ enc, const float* __restrict__ yhist,
    const float* __restrict__ Wa2,
    const float* __restrict__ Wfc, const float* __restrict__ bfc,
    const float* __restrict__ wih, const float* __restrict__ bih,
    const float* __restrict__ bhh,
    const float* __restrict__ Wff, const float* __restrict__ bff,
    float* __restrict__ ws, float* __restrict__ out) {

    __shared__ float hc[512];        // f32 state: h = [0,256), c = [256,512)
    __shared__ _Float16 hcf16[512] __attribute__((aligned(16)));
    __shared__ float z[256];
    __shared__ float red1[1024];     // P1 partials [4 chunks of 64 k][256 j]
    __shared__ float red2[1024];     // P2 partials [16 j-chunks][64 t]
    __shared__ float red3[1024];     // P3 partials [4 t-chunks][256 e]
    __shared__ float g2[1024];       // gate partials [kh<2][q'<512]
    __shared__ float attnw[64];
    __shared__ float wa2s[256];
    __shared__ float wfcs[257];
    __shared__ float ys[64];
    __shared__ float epl[16384];     // EPT[b] : [256 j][64 t]
    __shared__ float encl[16384];    // enc[b] : [64 t][256 e]

    const int bid  = blockIdx.x;
    const int b    = bid & 127;
    const int h1   = bid >> 7;       // owned state slice
    const int tid  = threadIdx.x;
    const int lane = tid & 63;
    const int wv   = tid >> 6;

    const _Float16* PKH = (const _Float16*)(ws + OFF_PKH);

    // ---- stage per-batch data into LDS once ----
    const float* EPTb = ws + OFF_EPT + b * 16384;
    const float* encb = enc + b * 16384;
    #pragma unroll
    for (int i = 0; i < 16; ++i) {
        epl[i * 1024 + tid]  = EPTb[i * 1024 + tid];
        encl[i * 1024 + tid] = encb[i * 1024 + tid];
    }
    if (tid < 512) { hc[tid] = 0.f; hcf16[tid] = (_Float16)0.f; }
    if (tid < 256) wa2s[tid] = Wa2[tid];
    if (tid < 257) wfcs[tid] = Wfc[tid];
    if (tid < NSTEP) ys[tid] = yhist[b * NSTEP + tid];
    const float bfc0 = bfc[0];
    // per-thread (tid<128) gate-row constants for the owned slice
    float wii = 0.f, wif = 0.f, wig = 0.f, wio = 0.f;
    float bsi = 0.f, bsf = 0.f, bsg = 0.f, bso = 0.f;
    if (tid < 128) {
        const int q0 = h1 * 128 + tid;
        wii = wih[q0];       bsi = bih[q0]       + bhh[q0];
        wif = wih[256 + q0]; bsf = bih[256 + q0] + bhh[256 + q0];
        wig = wih[512 + q0]; bsg = bih[512 + q0] + bhh[512 + q0];
        wio = wih[768 + q0]; bso = bih[768 + q0] + bhh[768 + q0];
    }
    __syncthreads();

    // P1: 4 chunks (c1) of 64 k within the OWNED k-set {h-slice, c-slice}
    const int c1 = tid >> 8, j1 = tid & 255;
    const int p1 = h1 + (c1 & 2);                 // c1 0,1 -> h part; 2,3 -> c part
    const h8_t* W1 = (const h8_t*)PKH + (p1 * 16 + (c1 & 1) * 8) * 256 + j1;
    const _Float16* hp1 = hcf16 + (c1 >> 1) * 256 + h1 * 128 + (c1 & 1) * 64;
    // P4: full-k gate dots; thread = (kh = tid>>9, q' = tid&511)
    const int kh = tid >> 9, qp = tid & 511;
    const h8_t* W4 = (const h8_t*)(PKH + 131072) + h1 * 16384 + kh * 512 + qp;
    const _Float16* hgk = hcf16 + kh * 128;

    // exchange buffers / flags
    float* ZXown  = ws + OFF_ZX + (b * 2 + h1) * 256;
    float* ZXpeer = ws + OFF_ZX + (b * 2 + (1 - h1)) * 256;
    float* HPown  = ws + OFF_HP + (b * 2 + h1) * 128;
    float* HPpeer = ws + OFF_HP + (b * 2 + (1 - h1)) * 128;
    unsigned* FLGown  = (unsigned*)(ws + OFF_FLAGS) + (b * 2 + h1) * 2;
    unsigned* FLGpeer = (unsigned*)(ws + OFF_FLAGS) + (b * 2 + (1 - h1)) * 2;

    for (int step = 0; step < NSTEP; ++step) {
        const unsigned tgt = (unsigned)(step + 1);
        // ---- Phase A: P1 partials over owned k (stream 128 KB) ----
        {
            float a0 = 0.f, a1 = 0.f;
            #pragma unroll 4
            for (int it = 0; it < 8; ++it) {
                h8_t w  = W1[it * 256];
                h8_t hv = *(const h8_t*)(hp1 + it * 8);   // wave-uniform broadcast
                a0 = FDOT2(h2of(w, 0), h2of(hv, 0), a0);
                a1 = FDOT2(h2of(w, 1), h2of(hv, 1), a1);
                a0 = FDOT2(h2of(w, 2), h2of(hv, 2), a0);
                a1 = FDOT2(h2of(w, 3), h2of(hv, 3), a1);
            }
            red1[c1 * 256 + j1] = a0 + a1;
        }
        // wait for peer h-slice (posted at end of peer's previous step)
        if (tid == 0 && step > 0) {
            while (atomicAdd(&FLGpeer[1], 0u) < (unsigned)step) { __builtin_amdgcn_s_sleep(1); }
        }
        __syncthreads();                                 // B1: red1 ready, peer-h flag seen
        // ---- Phase B: z-own combine+post (tid<256); peer-h read (tid 256..383) ----
        if (tid < 256) {
            float zown = red1[tid] + red1[256 + tid] + red1[512 + tid] + red1[768 + tid];
            z[tid] = zown;
            atomicExch(&ZXown[tid], zown);
        } else if (tid < 384 && step > 0) {
            const int i2 = tid - 256;
            float hp = atomicAdd(&HPpeer[i2], 0.f);
            const int ih = (1 - h1) * 128 + i2;
            hc[ih] = hp; hcf16[ih] = (_Float16)hp;
        }
        __syncthreads();                                 // B2: z posted + peer h in LDS
        if (tid == 0) atomicExch(&FLGown[0], tgt);       // z-flag

        // ---- Phase C: P4 full-k gate partials (stream 256 KB, hides z RTT) ----
        {
            float g0 = 0.f, g1 = 0.f;
            #pragma unroll 4
            for (int kk = 0; kk < 16; ++kk) {
                h8_t w  = W4[kk * 1024];
                h8_t hv = *(const h8_t*)(hgk + kk * 8);   // broadcast (kh wave-uniform)
                g0 = FDOT2(h2of(w, 0), h2of(hv, 0), g0);
                g1 = FDOT2(h2of(w, 1), h2of(hv, 1), g1);
                g0 = FDOT2(h2of(w, 2), h2of(hv, 2), g0);
                g1 = FDOT2(h2of(w, 3), h2of(hv, 3), g1);
            }
            g2[tid] = g0 + g1;                           // [kh*512 + q']
        }
        if (tid == 0) {
            while (atomicAdd(&FLGpeer[0], 0u) < tgt) { __builtin_amdgcn_s_sleep(1); }
        }
        __syncthreads();                                 // B3: g2 ready + peer z posted
        // ---- Phase D: z full ----
        if (tid < 256) {
            float zp = atomicAdd(&ZXpeer[tid], 0.f);
            z[tid] = z[tid] + zp;                        // commutative -> identical in pair
        }
        __syncthreads();                                 // B4: z ready

        // ---- Phase E: P2 scores partials ----
        {
            float partial = 0.f;
            const int jbase = wv * 16;
            #pragma unroll
            for (int jj = 0; jj < 16; ++jj) {
                const int j = jbase + jj;
                float v = epl[j * 64 + lane] + z[j];
                partial += ftanh(v) * wa2s[j];
            }
            red2[wv * 64 + lane] = partial;
        }
        __syncthreads();                                 // B5: red2 ready
        if (wv == 0) {
            float s = 0.f;
            #pragma unroll
            for (int w2 = 0; w2 < 16; ++w2) s += red2[w2 * 64 + lane];
            float m = s;
            #pragma unroll
            for (int d = 32; d >= 1; d >>= 1) m = fmaxf(m, __shfl_xor(m, d));
            float e = __expf(s - m);
            float su = e;
            #pragma unroll
            for (int d = 32; d >= 1; d >>= 1) su += __shfl_xor(su, d);
            attnw[lane] = e / su;
        }
        __syncthreads();                                 // B6: attnw ready
        // ---- Phase G: P3 ctx partials ----
        {
            const int e = tid & 255, tc = tid >> 8;
            float partial = 0.f;
            #pragma unroll
            for (int i = 0; i < 16; ++i) {
                const int t = tc * 16 + i;
                partial += attnw[t] * encl[t * 256 + e];
            }
            red3[tc * 256 + e] = partial;
        }
        __syncthreads();                                 // B7: red3 ready

        // ---- Phase H: ytil (per-wave redundant) + gates finalize + update ----
        float ytil;
        {
            float partial = 0.f;
            #pragma unroll
            for (int q = 0; q < 4; ++q) {
                const int e2 = q * 64 + lane;
                float cv = red3[e2] + red3[256 + e2] + red3[512 + e2] + red3[768 + e2];
                partial += cv * wfcs[e2];
            }
            #pragma unroll
            for (int d = 32; d >= 1; d >>= 1) partial += __shfl_xor(partial, d);
            ytil = partial + wfcs[256] * ys[step] + bfc0;
        }
        if (tid < 128) {
            float gi = g2[tid]       + g2[512 + tid] + ytil * wii + bsi;
            float gf = g2[128 + tid] + g2[640 + tid] + ytil * wif + bsf;
            float gg = g2[256 + tid] + g2[768 + tid] + ytil * wig + bsg;
            float go = g2[384 + tid] + g2[896 + tid] + ytil * wio + bso;
            const int ih = h1 * 128 + tid;
            float co = hc[256 + ih];
            float cn = fsig(gf) * co + fsig(gi) * ftanh(gg);
            float hn = fsig(go) * ftanh(cn);
            hc[ih] = hn; hc[256 + ih] = cn;
            hcf16[ih] = (_Float16)hn; hcf16[256 + ih] = (_Float16)cn;
            atomicExch(&HPown[tid], hn);                 // post own h-slice
        }
        __syncthreads();                                 // B8: state updated, h posted
        if (tid == 0) atomicExch(&FLGown[1], tgt);       // h-flag (consumed next step)
    }

    // ---- final h-exchange so the epilogue sees step-63 peer h ----
    if (tid == 0) {
        while (atomicAdd(&FLGpeer[1], 0u) < (unsigned)NSTEP) { __builtin_amdgcn_s_sleep(1); }
    }
    __syncthreads();
    if (tid < 128) {
        float hp = atomicAdd(&HPpeer[tid], 0.f);
        hc[(1 - h1) * 128 + tid] = hp;
    }
    __syncthreads();

    // ---- epilogue: only half 0 writes out ----
    if (h1 == 0 && wv < 2) {
        float partial = 0.f;
        #pragma unroll
        for (int qq = 0; qq < 8; ++qq) {
            const int e2 = qq * 64 + lane;
            float v;
            if (e2 < 256) {
                v = hc[e2];
            } else {
                const int e = e2 - 256;
                v = red3[e] + red3[256 + e] + red3[512 + e] + red3[768 + e];
            }
            partial += v * Wff[wv * 512 + e2];
        }
        #pragma unroll
        for (int d = 32; d >= 1; d >>= 1) partial += __shfl_xor(partial, d);
        if (lane == 0) out[b * 2 + wv] = partial + bff[wv];
    }
}

// ---------------------------------------------------------------------------
extern "C" void kernel_launch(void* const* d_in, const int* in_sizes, int n_in,
                              void* d_out, int out_size, void* d_ws, size_t ws_size,
                              hipStream_t stream) {
    const float* enc = (const float*)d_in[0];
    const float* yh  = (const float*)d_in[1];
    const float* Wa1 = (const float*)d_in[2];
    const float* ba1 = (const float*)d_in[3];
    const float* Wa2 = (const float*)d_in[4];
    // d_in[5] = b_a2 : softmax shift-invariant, unused
    const float* Wfc = (const float*)d_in[6];
    const float* bfc = (const float*)d_in[7];
    const float* Wih = (const float*)d_in[8];
    const float* Whh = (const float*)d_in[9];
    const float* bih = (const float*)d_in[10];
    const float* bhh = (const float*)d_in[11];
    const float* Wff = (const float*)d_in[12];
    const float* bff = (const float*)d_in[13];
    float* ws  = (float*)d_ws;
    float* out = (float*)d_out;

    hipLaunchKernelGGL(pack_weights, dim3(1792), dim3(256), 0, stream, Wa1, Whh, ws);
    hipLaunchKernelGGL(zero_flags, dim3(1), dim3(512), 0, stream, ws);
    hipLaunchKernelGGL(enc_proj_kernel, dim3(256), dim3(256), 0, stream, enc, ba1, ws);
    hipLaunchKernelGGL(decoder_main, dim3(256), dim3(1024), 0, stream,
                       enc, yh, Wa2, Wfc, bfc, Wih, bih, bhh, Wff, bff, ws, out);
}

// Round 10
// 470.954 us; speedup vs baseline: 1.5775x; 1.0747x over previous
//
#include <hip/hip_runtime.h>
#include <math.h>

// Problem constants
#define BATCH 128
#define TENC  64
#define NSTEP 63

// Workspace layout (FLOAT offsets)
#define OFF_WA1ET  0         // [256 k][256 j] f32 : W_a1[j][512+k]  (enc part, for enc_proj)
#define OFF_EPT    65536     // [128 b][256 j][64 t] f32
#define OFF_PKH    2162688   // fp16 region (half offsets within):
                             //   PK1: [0,131072)      = [p<4][kk<16][j<256][m<8] = Wa1[j][p*128+kk*8+m]
                             //   PKG: [131072,393216) = [h1<2][kk<16][kh<2][q'<512][m<8]
                             //        = Whh[q][k], q = (q'>>7)*256 + h1*128 + (q'&127), k = kh*128+kk*8+m
#define OFF_ZX     2359296   // [128 b][2 half][256] f32   z-half exchange (single-buffered, chain-safe)
#define OFF_HP     2424832   // [128 b][2 half][128] f32   h-slice exchange
#define OFF_FLAGS  2457600   // [128 b][2 half][2] uint    (monotonic; 0=z-flag, 1=h-flag)

typedef __attribute__((ext_vector_type(8))) _Float16 h8_t;
typedef __attribute__((ext_vector_type(2))) _Float16 h2_t;

#if defined(__has_builtin)
#if __has_builtin(__builtin_amdgcn_fdot2)
#define FDOT2(a, b, c) __builtin_amdgcn_fdot2((a), (b), (c), false)
#endif
#endif
#ifndef FDOT2
#define FDOT2(a, b, c) ((c) + (float)(a)[0] * (float)(b)[0] + (float)(a)[1] * (float)(b)[1])
#endif

__device__ __forceinline__ h2_t h2of(h8_t v, int i) {   // i must be literal (unrolled)
    h2_t r = {v[2 * i], v[2 * i + 1]};
    return r;
}
__device__ __forceinline__ float ftanh(float x) {
    x = fminf(15.f, fmaxf(-15.f, x));
    float e = __expf(2.f * x);
    return (e - 1.f) * __builtin_amdgcn_rcpf(e + 1.f);
}
__device__ __forceinline__ float fsig(float x) {
    return __builtin_amdgcn_rcpf(1.f + __expf(-x));
}

// ---------------------------------------------------------------------------
// Pre-kernel A: pack weights (fp16 stream-ordered) + WA1ET (f32)
// ---------------------------------------------------------------------------
__global__ void pack_weights(const float* __restrict__ Wa1,
                             const float* __restrict__ Whh,
                             float* __restrict__ ws) {
    int idx = blockIdx.x * blockDim.x + threadIdx.x;
    _Float16* PKH = (_Float16*)(ws + OFF_PKH);
    if (idx < 131072) {
        int m = idx & 7, j = (idx >> 3) & 255, kk = (idx >> 11) & 15, p = idx >> 15;
        int k = p * 128 + kk * 8 + m;
        PKH[idx] = (_Float16)Wa1[j * 768 + k];
    } else if (idx < 393216) {
        int n = idx - 131072;
        int m = n & 7, qp = (n >> 3) & 511, kh = (n >> 12) & 1, kk = (n >> 13) & 15, h1 = n >> 17;
        int q = ((qp >> 7) << 8) + h1 * 128 + (qp & 127);
        int k = kh * 128 + kk * 8 + m;
        PKH[131072 + n] = (_Float16)Whh[q * 256 + k];
    } else if (idx < 458752) {
        int n = idx - 393216;
        int k = n >> 8, j = n & 255;
        ws[OFF_WA1ET + n] = Wa1[j * 768 + 512 + k];
    }
}

// Pre-kernel A2: zero the exchange flags (every launch, before decoder)
__global__ void zero_flags(float* __restrict__ ws) {
    unsigned* f = (unsigned*)(ws + OFF_FLAGS);
    f[threadIdx.x] = 0u;   // 512 = [128][2][2]
}

// ---------------------------------------------------------------------------
// Pre-kernel B: EPT[b][j][t] = b_a1[j] + sum_k enc[b][t][k] * W_a1[j][512+k]
// ---------------------------------------------------------------------------
__global__ void enc_proj_kernel(const float* __restrict__ enc,
                                const float* __restrict__ ba1,
                                float* __restrict__ ws) {
    __shared__ float smem[8448];
    const int b  = blockIdx.x >> 1;
    const int th = blockIdx.x & 1;
    const int t0 = th * 32;
    const int tid = threadIdx.x;

    const float* encb = enc + (b * TENC + t0) * 256;
    for (int c = 0; c < 32; ++c) smem[c * 256 + tid] = encb[c * 256 + tid];
    __syncthreads();

    const int w = tid >> 6, l = tid & 63;
    float acc[8][4];
    #pragma unroll
    for (int a = 0; a < 8; ++a)
        #pragma unroll
        for (int c = 0; c < 4; ++c) acc[a][c] = 0.f;

    const float4* WT = (const float4*)(ws + OFF_WA1ET);
    for (int k = 0; k < 256; ++k) {
        float4 wv = WT[k * 64 + l];
        #pragma unroll
        for (int tt = 0; tt < 8; ++tt) {
            float e = smem[(w * 8 + tt) * 256 + k];
            acc[tt][0] += e * wv.x; acc[tt][1] += e * wv.y;
            acc[tt][2] += e * wv.z; acc[tt][3] += e * wv.w;
        }
    }
    float4 bb = ((const float4*)ba1)[l];
    __syncthreads();
    #pragma unroll
    for (int tt = 0; tt < 8; ++tt) {
        smem[(4 * l + 0) * 33 + w * 8 + tt] = acc[tt][0] + bb.x;
        smem[(4 * l + 1) * 33 + w * 8 + tt] = acc[tt][1] + bb.y;
        smem[(4 * l + 2) * 33 + w * 8 + tt] = acc[tt][2] + bb.z;
        smem[(4 * l + 3) * 33 + w * 8 + tt] = acc[tt][3] + bb.w;
    }
    __syncthreads();
    float* EPT = ws + OFF_EPT + b * 16384;
    for (int c = 0; c < 32; ++c) {
        int i = c * 256 + tid;
        int j = i >> 5, t5 = i & 31;
        EPT[j * 64 + t0 + t5] = smem[j * 33 + t5];
    }
}

// ---------------------------------------------------------------------------
// Main kernel: 256 WGs = 2 per batch; WG h1 owns state slice [h1*128, +128).
// P3 (context GEMV) is REMOVED from the step loop: ytil = sum_t attn[t]*encw[t]
// with encw[t] = enc[t]·wfcs precomputed (context only materialized once,
// post-loop, for the epilogue). Exchanges: z-partials (hidden under P4 stream)
// and the 128-f32 h-slice (hidden under step turnaround).
// ---------------------------------------------------------------------------
__global__ __launch_bounds__(1024, 4) void decoder_main(
    const float* __restrict__ enc, const float* __restrict__ yhist,
    const float* __restrict__ Wa2,
    const float* __restrict__ Wfc, const float* __restrict__ bfc,
    const float* __restrict__ wih, const float* __restrict__ bih,
    const float* __restrict__ bhh,
    const float* __restrict__ Wff, const float* __restrict__ bff,
    float* __restrict__ ws, float* __restrict__ out) {

    __shared__ float hc[512];        // f32 state: h = [0,256), c = [256,512)
    __shared__ _Float16 hcf16[512] __attribute__((aligned(16)));
    __shared__ float z[256];
    __shared__ float red1[1024];     // P1 partials / scratch
    __shared__ float red2[1024];     // P2 partials [16 j-chunks][64 t]
    __shared__ float g2[1024];       // gate partials [kh<2][q'<512]
    __shared__ float attnw[64];
    __shared__ float encw[64];       // enc[t]·wfcs  (P3-elimination vector)
    __shared__ float wa2s[256];
    __shared__ float wfcs[257];
    __shared__ float ys[64];
    __shared__ float ytil_s;
    __shared__ float epl[16384];     // EPT[b] : [256 j][64 t]

    const int bid  = blockIdx.x;
    const int b    = bid & 127;
    const int h1   = bid >> 7;       // owned state slice
    const int tid  = threadIdx.x;
    const int lane = tid & 63;
    const int wv   = tid >> 6;

    const _Float16* PKH = (const _Float16*)(ws + OFF_PKH);

    // ---- stage per-batch data into LDS once ----
    const float* EPTb = ws + OFF_EPT + b * 16384;
    const float* encb = enc + b * 16384;
    #pragma unroll
    for (int i = 0; i < 16; ++i) {
        epl[i * 1024 + tid] = EPTb[i * 1024 + tid];
    }
    if (tid < 512) { hc[tid] = 0.f; hcf16[tid] = (_Float16)0.f; }
    if (tid < 256) wa2s[tid] = Wa2[tid];
    if (tid < 257) wfcs[tid] = Wfc[tid];
    if (tid < NSTEP) ys[tid] = yhist[b * NSTEP + tid];
    const float bfc0 = bfc[0];
    // per-thread (tid<128) gate-row constants for the owned slice
    float wii = 0.f, wif = 0.f, wig = 0.f, wio = 0.f;
    float bsi = 0.f, bsf = 0.f, bsg = 0.f, bso = 0.f;
    if (tid < 128) {
        const int q0 = h1 * 128 + tid;
        wii = wih[q0];       bsi = bih[q0]       + bhh[q0];
        wif = wih[256 + q0]; bsf = bih[256 + q0] + bhh[256 + q0];
        wig = wih[512 + q0]; bsg = bih[512 + q0] + bhh[512 + q0];
        wio = wih[768 + q0]; bso = bih[768 + q0] + bhh[768 + q0];
    }
    // encw partials: thread (t = tid>>4, cch = tid&15) covers 16 e-values.
    // Reads Wfc straight from global (no ordering dep on wfcs staging).
    {
        const int t = tid >> 4, cch = tid & 15;
        float p = 0.f;
        #pragma unroll
        for (int i = 0; i < 16; ++i)
            p += encb[t * 256 + cch * 16 + i] * Wfc[cch * 16 + i];
        red1[t * 16 + cch] = p;
    }
    __syncthreads();
    if (tid < 64) {
        float s = 0.f;
        #pragma unroll
        for (int c = 0; c < 16; ++c) s += red1[tid * 16 + c];
        encw[tid] = s;
    }
    __syncthreads();

    // P1: 4 chunks (c1) of 64 k within the OWNED k-set {h-slice, c-slice}
    const int c1 = tid >> 8, j1 = tid & 255;
    const int p1 = h1 + (c1 & 2);                 // c1 0,1 -> h part; 2,3 -> c part
    const h8_t* W1 = (const h8_t*)PKH + (p1 * 16 + (c1 & 1) * 8) * 256 + j1;
    const _Float16* hp1 = hcf16 + (c1 >> 1) * 256 + h1 * 128 + (c1 & 1) * 64;
    // P4: full-k gate dots; thread = (kh = tid>>9, q' = tid&511)
    const int kh = tid >> 9, qp = tid & 511;
    const h8_t* W4 = (const h8_t*)(PKH + 131072) + h1 * 16384 + kh * 512 + qp;
    const _Float16* hgk = hcf16 + kh * 128;

    // exchange buffers / flags
    float* ZXown  = ws + OFF_ZX + (b * 2 + h1) * 256;
    float* ZXpeer = ws + OFF_ZX + (b * 2 + (1 - h1)) * 256;
    float* HPown  = ws + OFF_HP + (b * 2 + h1) * 128;
    float* HPpeer = ws + OFF_HP + (b * 2 + (1 - h1)) * 128;
    unsigned* FLGown  = (unsigned*)(ws + OFF_FLAGS) + (b * 2 + h1) * 2;
    unsigned* FLGpeer = (unsigned*)(ws + OFF_FLAGS) + (b * 2 + (1 - h1)) * 2;

    for (int step = 0; step < NSTEP; ++step) {
        const unsigned tgt = (unsigned)(step + 1);
        // ---- Phase A: P1 partials over owned k (stream 128 KB) ----
        {
            float a0 = 0.f, a1 = 0.f;
            #pragma unroll 4
            for (int it = 0; it < 8; ++it) {
                h8_t w  = W1[it * 256];
                h8_t hv = *(const h8_t*)(hp1 + it * 8);   // wave-uniform broadcast
                a0 = FDOT2(h2of(w, 0), h2of(hv, 0), a0);
                a1 = FDOT2(h2of(w, 1), h2of(hv, 1), a1);
                a0 = FDOT2(h2of(w, 2), h2of(hv, 2), a0);
                a1 = FDOT2(h2of(w, 3), h2of(hv, 3), a1);
            }
            red1[c1 * 256 + j1] = a0 + a1;
        }
        // wait for peer h-slice (posted at end of peer's previous step)
        if (tid == 0 && step > 0) {
            while (atomicAdd(&FLGpeer[1], 0u) < (unsigned)step) { __builtin_amdgcn_s_sleep(1); }
        }
        __syncthreads();                                 // B1: red1 ready, peer-h flag seen
        // ---- Phase B: z-own combine+post (tid<256); peer-h read (tid 256..383) ----
        if (tid < 256) {
            float zown = red1[tid] + red1[256 + tid] + red1[512 + tid] + red1[768 + tid];
            z[tid] = zown;
            atomicExch(&ZXown[tid], zown);
        } else if (tid < 384 && step > 0) {
            const int i2 = tid - 256;
            float hp = atomicAdd(&HPpeer[i2], 0.f);
            const int ih = (1 - h1) * 128 + i2;
            hc[ih] = hp; hcf16[ih] = (_Float16)hp;
        }
        __syncthreads();                                 // B2: z posted + peer h in LDS
        if (tid == 0) atomicExch(&FLGown[0], tgt);       // z-flag

        // ---- Phase C: P4 full-k gate partials (stream 256 KB, hides z RTT) ----
        {
            float g0 = 0.f, g1 = 0.f;
            #pragma unroll 4
            for (int kk = 0; kk < 16; ++kk) {
                h8_t w  = W4[kk * 1024];
                h8_t hv = *(const h8_t*)(hgk + kk * 8);   // broadcast (kh wave-uniform)
                g0 = FDOT2(h2of(w, 0), h2of(hv, 0), g0);
                g1 = FDOT2(h2of(w, 1), h2of(hv, 1), g1);
                g0 = FDOT2(h2of(w, 2), h2of(hv, 2), g0);
                g1 = FDOT2(h2of(w, 3), h2of(hv, 3), g1);
            }
            g2[tid] = g0 + g1;                           // [kh*512 + q']
        }
        if (tid == 0) {
            while (atomicAdd(&FLGpeer[0], 0u) < tgt) { __builtin_amdgcn_s_sleep(1); }
        }
        __syncthreads();                                 // B3: g2 ready + peer z posted
        // ---- Phase D: z full ----
        if (tid < 256) {
            float zp = atomicAdd(&ZXpeer[tid], 0.f);
            z[tid] = z[tid] + zp;                        // commutative -> identical in pair
        }
        __syncthreads();                                 // B4: z ready

        // ---- Phase E: P2 scores partials ----
        {
            float partial = 0.f;
            const int jbase = wv * 16;
            #pragma unroll
            for (int jj = 0; jj < 16; ++jj) {
                const int j = jbase + jj;
                float v = epl[j * 64 + lane] + z[j];
                partial += ftanh(v) * wa2s[j];
            }
            red2[wv * 64 + lane] = partial;
        }
        __syncthreads();                                 // B5: red2 ready
        // ---- Phase F: wave 0 = softmax + ytil (encw dot, no ctx GEMV) ----
        if (wv == 0) {
            float s = 0.f;
            #pragma unroll
            for (int w2 = 0; w2 < 16; ++w2) s += red2[w2 * 64 + lane];
            float m = s;
            #pragma unroll
            for (int d = 32; d >= 1; d >>= 1) m = fmaxf(m, __shfl_xor(m, d));
            float e = __expf(s - m);
            float su = e;
            #pragma unroll
            for (int d = 32; d >= 1; d >>= 1) su += __shfl_xor(su, d);
            float a = e * __builtin_amdgcn_rcpf(su);
            attnw[lane] = a;
            float yp = a * encw[lane];
            #pragma unroll
            for (int d = 32; d >= 1; d >>= 1) yp += __shfl_xor(yp, d);
            if (lane == 0) ytil_s = yp + wfcs[256] * ys[step] + bfc0;
        }
        __syncthreads();                                 // B6: ytil + attnw ready

        // ---- Phase H: gates finalize + state update + h-post (tid<128) ----
        if (tid < 128) {
            const float ytil = ytil_s;
            float gi = g2[tid]       + g2[512 + tid] + ytil * wii + bsi;
            float gf = g2[128 + tid] + g2[640 + tid] + ytil * wif + bsf;
            float gg = g2[256 + tid] + g2[768 + tid] + ytil * wig + bsg;
            float go = g2[384 + tid] + g2[896 + tid] + ytil * wio + bso;
            const int ih = h1 * 128 + tid;
            float co = hc[256 + ih];
            float cn = fsig(gf) * co + fsig(gi) * ftanh(gg);
            float hn = fsig(go) * ftanh(cn);
            hc[ih] = hn; hc[256 + ih] = cn;
            hcf16[ih] = (_Float16)hn; hcf16[256 + ih] = (_Float16)cn;
            atomicExch(&HPown[tid], hn);                 // post own h-slice
        }
        __syncthreads();                                 // B7: state updated, h posted
        if (tid == 0) atomicExch(&FLGown[1], tgt);       // h-flag (consumed next step)
    }

    // ---- final h-exchange so the epilogue sees step-63 peer h ----
    if (tid == 0) {
        while (atomicAdd(&FLGpeer[1], 0u) < (unsigned)NSTEP) { __builtin_amdgcn_s_sleep(1); }
    }
    __syncthreads();
    if (tid < 128) {
        float hp = atomicAdd(&HPpeer[tid], 0.f);
        hc[(1 - h1) * 128 + tid] = hp;
    }
    __syncthreads();

    // ---- epilogue (h1 == 0 only): materialize final ctx from L2, then out ----
    if (h1 == 0) {
        if (tid < 256) {
            float cv = 0.f;
            #pragma unroll 8
            for (int t = 0; t < TENC; ++t)
                cv += attnw[t] * encb[t * 256 + tid];
            red1[tid] = cv;
        }
        __syncthreads();
        if (wv < 2) {
            float partial = 0.f;
            #pragma unroll
            for (int qq = 0; qq < 8; ++qq) {
                const int e2 = qq * 64 + lane;
                float v = (e2 < 256) ? hc[e2] : red1[e2 - 256];
                partial += v * Wff[wv * 512 + e2];
            }
            #pragma unroll
            for (int d = 32; d >= 1; d >>= 1) partial += __shfl_xor(partial, d);
            if (lane == 0) out[b * 2 + wv] = partial + bff[wv];
        }
    }
}

// ---------------------------------------------------------------------------
extern "C" void kernel_launch(void* const* d_in, const int* in_sizes, int n_in,
                              void* d_out, int out_size, void* d_ws, size_t ws_size,
                              hipStream_t stream) {
    const float* enc = (const float*)d_in[0];
    const float* yh  = (const float*)d_in[1];
    const float* Wa1 = (const float*)d_in[2];
    const float* ba1 = (const float*)d_in[3];
    const float* Wa2 = (const float*)d_in[4];
    // d_in[5] = b_a2 : softmax shift-invariant, unused
    const float* Wfc = (const float*)d_in[6];
    const float* bfc = (const float*)d_in[7];
    const float* Wih = (const float*)d_in[8];
    const float* Whh = (const float*)d_in[9];
    const float* bih = (const float*)d_in[10];
    const float* bhh = (const float*)d_in[11];
    const float* Wff = (const float*)d_in[12];
    const float* bff = (const float*)d_in[13];
    float* ws  = (float*)d_ws;
    float* out = (float*)d_out;

    hipLaunchKernelGGL(pack_weights, dim3(1792), dim3(256), 0, stream, Wa1, Whh, ws);
    hipLaunchKernelGGL(zero_flags, dim3(1), dim3(512), 0, stream, ws);
    hipLaunchKernelGGL(enc_proj_kernel, dim3(256), dim3(256), 0, stream, enc, ba1, ws);
    hipLaunchKernelGGL(decoder_main, dim3(256), dim3(1024), 0, stream,
                       enc, yh, Wa2, Wfc, bfc, Wih, bih, bhh, Wff, bff, ws, out);
}